// Round 1
// baseline (364.812 us; speedup 1.0000x reference)
//
#include <hip/hip_runtime.h>
#include <hip/hip_bf16.h>

#define T_LEN 200
#define F_IN 64
#define A_IN 128
#define H 100
#define H4 400
#define OUT_N 10
#define ROWS 16

typedef __attribute__((ext_vector_type(8))) short bf16x8;
typedef __attribute__((ext_vector_type(4))) float f32x4;

__device__ __forceinline__ unsigned short f2bf(float f) {
    union { float f; unsigned u; } v; v.f = f;
    unsigned r = v.u + 0x7FFFu + ((v.u >> 16) & 1u);
    return (unsigned short)(r >> 16);
}

__device__ __forceinline__ float sigm(float x) {
    return 1.0f / (1.0f + __expf(-x));
}

extern "C" __global__ void __launch_bounds__(512, 2)
traj_kernel(const float* __restrict__ attrs, const float* __restrict__ seq,
            const float* __restrict__ Wd, const float* __restrict__ bd,
            const float* __restrict__ Wk, const float* __restrict__ Wr,
            const float* __restrict__ bl, const float* __restrict__ W1,
            const float* __restrict__ b1, const float* __restrict__ W2,
            const float* __restrict__ b2, const float* __restrict__ Wc,
            const float* __restrict__ bc, float* __restrict__ out)
{
    // LDS map (bytes):
    //   [0, 25664)      zb   float[16][401]   (z exchange, pad 401 -> conflict-free)
    //   [25664, 29760)  hl   ushort[4][64][8] (h bf16 A-fragments, persists across loop)
    //   [29760, 36160)  h32  float[16][100]   (final h fp32)
    // epilogue aliases (loop-dead regions):
    //   att  float[16][128] @0, catb float[16][200] @8192, x1b float[16][100] @20992
    //   x2b  float[16][50]  @0, lgb  float[16][10]  @3200
    __shared__ __align__(16) char smem[36160];
    float* zb = (float*)smem;
    unsigned short* hl = (unsigned short*)(smem + 25664);
    float* h32 = (float*)(smem + 29760);

    const int tid = threadIdx.x;
    const int lane = tid & 63;
    const int w = tid >> 6;
    const int ln15 = lane & 15;
    const int lg = lane >> 4;
    const int b0 = blockIdx.x * ROWS;

    // n-tile assignment over 8 waves: w0 gets 4 tiles, w1..w7 get 3 each (25 total)
    const int nt0 = (w == 0) ? 0 : 1 + 3 * w;
    const int ntc = (w == 0) ? 4 : 3;

    // ---- pack weight B-fragments into registers (one-time) ----
    // B-frag layout (16x16x32): lane holds col n = lane&15, k = (lane>>4)*8 + i
    bf16x8 wkf[4][2];
    bf16x8 wrf[4][4];
#pragma unroll
    for (int q = 0; q < 4; q++) {
        const bool v = (q < ntc);
        const int n = v ? ((nt0 + q) * 16 + ln15) : 0;
#pragma unroll
        for (int kt = 0; kt < 2; kt++) {
            bf16x8 f;
#pragma unroll
            for (int i = 0; i < 8; i++) {
                int k = kt * 32 + lg * 8 + i;
                float x = v ? Wk[k * H4 + n] : 0.0f;
                f[i] = (short)f2bf(x);
            }
            wkf[q][kt] = f;
        }
#pragma unroll
        for (int kt = 0; kt < 4; kt++) {
            bf16x8 f;
#pragma unroll
            for (int i = 0; i < 8; i++) {
                int k = kt * 32 + lg * 8 + i;
                float x = (v && k < H) ? Wr[k * H4 + n] : 0.0f;  // zero-pad k=100..127
                f[i] = (short)f2bf(x);
            }
            wrf[q][kt] = f;
        }
    }

    // ---- gate-thread state: element e = tid + 512*k, e < 1600; b = e&15, j = e>>4 ----
    float bi0[4], bf0[4], bg0[4], bo0[4];
    float creg[4];
#pragma unroll
    for (int k = 0; k < 4; k++) {
        creg[k] = 0.0f;
        int e = tid + 512 * k;
        if (e < ROWS * H) {
            int j = e >> 4;
            bi0[k] = bl[j]; bf0[k] = bl[H + j]; bg0[k] = bl[2 * H + j]; bo0[k] = bl[3 * H + j];
        } else { bi0[k] = 0; bf0[k] = 0; bg0[k] = 0; bo0[k] = 0; }
    }

    // zero h fragments (k>=100 padding stays zero forever)
    for (int i = tid; i < 4 * 64 * 8; i += 512) hl[i] = 0;
    __syncthreads();

    // seq A-frag addressing: lane holds row = lane&15, k(feature) = lg*8 + i
    const float* seqr = seq + (size_t)(b0 + ln15) * (T_LEN * F_IN);
    const int o0 = lg * 8;

    f32x4 s0, s1, s2, s3;
    {
        const float* p = seqr + o0;
        s0 = *(const f32x4*)(p);
        s1 = *(const f32x4*)(p + 4);
        s2 = *(const f32x4*)(p + 32);
        s3 = *(const f32x4*)(p + 36);
    }

    for (int t = 0; t < T_LEN; t++) {
        // convert staged seq floats to bf16 A-fragments
        bf16x8 a0, a1;
#pragma unroll
        for (int i = 0; i < 4; i++) {
            a0[i]     = (short)f2bf(s0[i]);
            a0[4 + i] = (short)f2bf(s1[i]);
            a1[i]     = (short)f2bf(s2[i]);
            a1[4 + i] = (short)f2bf(s3[i]);
        }

        // load h(t-1) fragments
        bf16x8 hf0 = *(const bf16x8*)(hl + (0 * 64 + lane) * 8);
        bf16x8 hf1 = *(const bf16x8*)(hl + (1 * 64 + lane) * 8);
        bf16x8 hf2 = *(const bf16x8*)(hl + (2 * 64 + lane) * 8);
        bf16x8 hf3 = *(const bf16x8*)(hl + (3 * 64 + lane) * 8);

        // prefetch seq tile for t+1 (latency hidden under MFMAs + gate phase)
        if (t < T_LEN - 1) {
            const float* p = seqr + (t + 1) * F_IN + o0;
            s0 = *(const f32x4*)(p);
            s1 = *(const f32x4*)(p + 4);
            s2 = *(const f32x4*)(p + 32);
            s3 = *(const f32x4*)(p + 36);
        }

        // z = seq_t @ Wk + h @ Wr  (bias added in gate phase)
        f32x4 acc[4];
#pragma unroll
        for (int q = 0; q < 4; q++) {
            if (q < ntc) {
                f32x4 a = {0.f, 0.f, 0.f, 0.f};
                a = __builtin_amdgcn_mfma_f32_16x16x32_bf16(a0,  wkf[q][0], a, 0, 0, 0);
                a = __builtin_amdgcn_mfma_f32_16x16x32_bf16(a1,  wkf[q][1], a, 0, 0, 0);
                a = __builtin_amdgcn_mfma_f32_16x16x32_bf16(hf0, wrf[q][0], a, 0, 0, 0);
                a = __builtin_amdgcn_mfma_f32_16x16x32_bf16(hf1, wrf[q][1], a, 0, 0, 0);
                a = __builtin_amdgcn_mfma_f32_16x16x32_bf16(hf2, wrf[q][2], a, 0, 0, 0);
                a = __builtin_amdgcn_mfma_f32_16x16x32_bf16(hf3, wrf[q][3], a, 0, 0, 0);
                acc[q] = a;
            }
        }

        // scatter z to LDS: D-frag row = lg*4 + r, col = nt*16 + (lane&15)
#pragma unroll
        for (int q = 0; q < 4; q++) {
            if (q < ntc) {
                const int col = (nt0 + q) * 16 + ln15;
#pragma unroll
                for (int r = 0; r < 4; r++) {
                    zb[(lg * 4 + r) * 401 + col] = acc[q][r];
                }
            }
        }
        __syncthreads();

        // gate phase (fp32): i,f,o = sigmoid; g = relu; c = f*c + i*g; h = o*relu(c)
        const bool last = (t == T_LEN - 1);
#pragma unroll
        for (int k = 0; k < 4; k++) {
            int e = tid + 512 * k;
            if (e < ROWS * H) {
                int b = e & 15, j = e >> 4;
                float zi = zb[b * 401 + j] + bi0[k];
                float zf = zb[b * 401 + H + j] + bf0[k];
                float zg = zb[b * 401 + 2 * H + j] + bg0[k];
                float zo = zb[b * 401 + 3 * H + j] + bo0[k];
                float ii = sigm(zi), ff = sigm(zf), oo = sigm(zo);
                float gg = fmaxf(zg, 0.0f);
                float c = ff * creg[k] + ii * gg;
                creg[k] = c;
                float h = oo * fmaxf(c, 0.0f);
                // h A-frag position: ktile = j>>5, lane = b + 16*((j>>3)&3), elem = j&7
                hl[((j >> 5) * 64 + (b + 16 * ((j >> 3) & 3))) * 8 + (j & 7)] = f2bf(h);
                if (last) h32[b * H + j] = h;
            }
        }
        __syncthreads();
    }

    // ---- epilogue: fp32 dense chain + softmax (tiny: ~0.6 MFLOP/block) ----
    float* att  = (float*)smem;            // [16][128]
    float* catb = (float*)(smem + 8192);   // [16][200]
    float* x1b  = (float*)(smem + 20992);  // [16][100]
    float* x2b  = (float*)smem;            // [16][50]
    float* lgb  = (float*)(smem + 3200);   // [16][10]

    {
        const f32x4* src = (const f32x4*)(attrs + (size_t)b0 * A_IN);
        f32x4* dst = (f32x4*)att;
        dst[tid] = src[tid];   // 512 * 16B = 16x128 floats
    }
    __syncthreads();

#pragma unroll
    for (int k = 0; k < 4; k++) {
        int e = tid + 512 * k;
        if (e < ROWS * H) {
            int b = e & 15, j = e >> 4;
            float s = bd[j];
            for (int kk = 0; kk < A_IN; kk++) s += att[b * A_IN + kk] * Wd[kk * H + j];
            catb[b * 200 + j] = fmaxf(s, 0.0f);
            catb[b * 200 + H + j] = h32[b * H + j];
        }
    }
    __syncthreads();

#pragma unroll
    for (int k = 0; k < 4; k++) {
        int e = tid + 512 * k;
        if (e < ROWS * H) {
            int b = e & 15, j = e >> 4;
            float s = b1[j];
            for (int kk = 0; kk < 200; kk++) s += catb[b * 200 + kk] * W1[kk * H + j];
            x1b[b * H + j] = fmaxf(s, 0.0f);
        }
    }
    __syncthreads();

#pragma unroll
    for (int k = 0; k < 2; k++) {
        int e = tid + 512 * k;
        if (e < ROWS * 50) {
            int b = e & 15, j = e >> 4;
            float s = b2[j];
            for (int kk = 0; kk < H; kk++) s += x1b[b * H + kk] * W2[kk * 50 + j];
            x2b[b * 50 + j] = fmaxf(s, 0.0f);
        }
    }
    __syncthreads();

    if (tid < ROWS * OUT_N) {
        int b = tid / OUT_N, o = tid % OUT_N;
        float s = bc[o];
        for (int kk = 0; kk < 50; kk++) s += x2b[b * 50 + kk] * Wc[kk * OUT_N + o];
        lgb[b * OUT_N + o] = s;
    }
    __syncthreads();

    if (tid < ROWS) {
        int b = tid;
        float m = -1e30f;
        float v[10];
#pragma unroll
        for (int o = 0; o < 10; o++) { v[o] = lgb[b * 10 + o]; m = fmaxf(m, v[o]); }
        float ssum = 0.0f;
#pragma unroll
        for (int o = 0; o < 10; o++) { v[o] = __expf(v[o] - m); ssum += v[o]; }
        float inv = 1.0f / ssum;
#pragma unroll
        for (int o = 0; o < 10; o++) out[(size_t)(b0 + b) * 10 + o] = v[o] * inv;
    }
}

extern "C" void kernel_launch(void* const* d_in, const int* in_sizes, int n_in,
                              void* d_out, int out_size, void* d_ws, size_t ws_size,
                              hipStream_t stream) {
    const float* attrs = (const float*)d_in[0];
    const float* seq   = (const float*)d_in[1];
    const float* Wd    = (const float*)d_in[2];
    const float* bd    = (const float*)d_in[3];
    const float* Wk    = (const float*)d_in[4];
    const float* Wr    = (const float*)d_in[5];
    const float* bl    = (const float*)d_in[6];
    const float* W1    = (const float*)d_in[7];
    const float* b1    = (const float*)d_in[8];
    const float* W2    = (const float*)d_in[9];
    const float* b2    = (const float*)d_in[10];
    const float* Wc    = (const float*)d_in[11];
    const float* bc    = (const float*)d_in[12];
    float* out = (float*)d_out;

    hipLaunchKernelGGL(traj_kernel, dim3(256), dim3(512), 0, stream,
                       attrs, seq, Wd, bd, Wk, Wr, bl, W1, b1, W2, b2, Wc, bc, out);
}